// Round 2
// baseline (303.436 us; speedup 1.0000x reference)
//
#include <hip/hip_runtime.h>

namespace {

constexpr int kB = 4, kCin = 4, kCout = 4;
constexpr int kD1 = 32, kD2 = 32, kH = 64, kW = 64;
constexpr int kHO = kH / 2, kWO = kW / 2;              // 32, 32
constexpr int kWElems = kCout * kCin * 3 * 3 * 2 * 2;  // 576
constexpr int kSlice = kH * kW;                        // 4096 floats per (d1,d2) slice
constexpr int kCiStride = kD1 * kD2 * kSlice;          // x ci stride in floats

__global__ __launch_bounds__(256)
void conv4d_strang(const float* __restrict__ x,
                   const float* __restrict__ w,
                   const float* __restrict__ bias,
                   float* __restrict__ y)
{
    __shared__ float wlds[kWElems];
    {
        const int tid = threadIdx.y * 8 + threadIdx.x;
        for (int i = tid; i < kWElems; i += 256) wlds[i] = w[i];
    }
    __syncthreads();

    const int quad = threadIdx.x;              // 0..7  -> wo0 = quad*4
    const int ho   = threadIdx.y;              // 0..31
    const int v    = blockIdx.x;               // 0..31
    const int u    = blockIdx.y;               // 0..31
    const int b    = blockIdx.z;               // 0..3

    const int h0  = 2 * ho;
    const int w0  = 8 * quad;                  // 8 input floats -> 4 outputs

    // acc[co][col]
    float acc[kCout][4];
    #pragma unroll
    for (int co = 0; co < kCout; ++co)
        #pragma unroll
        for (int c = 0; c < 4; ++c) acc[co][c] = 0.f;

    // x base for this (b, h0, w0), ci=0, d1=d2=0
    const float* xbase = x + (size_t)b * kCin * kCiStride / kCin * kCin  // b*kCin*kD1*kD2*kSlice
                           ;
    // (rewrite cleanly)
    const float* xb = x + ((size_t)b * kCin) * (size_t)kCiStride / 1;   // b * Cin*D1*D2*H*W? no —
    // Correct base: x[b][ci][d1][d2][h][w]; we fold (h0,w0) here:
    const float* xbh = x + ((size_t)b * kCin * kD1 * kD2) * kSlice + (size_t)h0 * kW + w0;

    #pragma unroll
    for (int ku = 0; ku < 3; ++ku) {
        const int d1 = u + ku - 1;
        if (d1 < 0 || d1 >= kD1) continue;                 // wave-uniform
        #pragma unroll
        for (int kv = 0; kv < 3; ++kv) {
            const int d2 = v + kv - 1;
            if (d2 < 0 || d2 >= kD2) continue;             // wave-uniform
            const float* ps = xbh + (size_t)(d1 * kD2 + d2) * kSlice;
            #pragma unroll
            for (int ci = 0; ci < kCin; ++ci) {
                const float* xp = ps + (size_t)ci * kCiStride;
                const float4 r0a = *reinterpret_cast<const float4*>(xp);
                const float4 r0b = *reinterpret_cast<const float4*>(xp + 4);
                const float4 r1a = *reinterpret_cast<const float4*>(xp + kW);
                const float4 r1b = *reinterpret_cast<const float4*>(xp + kW + 4);
                #pragma unroll
                for (int co = 0; co < kCout; ++co) {
                    const float4 wv = *reinterpret_cast<const float4*>(
                        &wlds[(((co * kCin + ci) * 3 + ku) * 3 + kv) * 4]);
                    acc[co][0] += r0a.x * wv.x + r0a.y * wv.y + r1a.x * wv.z + r1a.y * wv.w;
                    acc[co][1] += r0a.z * wv.x + r0a.w * wv.y + r1a.z * wv.z + r1a.w * wv.w;
                    acc[co][2] += r0b.x * wv.x + r0b.y * wv.y + r1b.x * wv.z + r1b.y * wv.w;
                    acc[co][3] += r0b.z * wv.x + r0b.w * wv.y + r1b.z * wv.z + r1b.w * wv.w;
                }
            }
        }
    }

    const size_t co_stride = (size_t)kD1 * kD2 * kHO * kWO;  // 1,048,576
    const size_t obase =
        ((((size_t)b * kCout) * kD1 + u) * kD2 + v) * (size_t)(kHO * kWO)
        + (size_t)ho * kWO + (size_t)quad * 4;
    #pragma unroll
    for (int co = 0; co < kCout; ++co) {
        const float bc = bias[co];
        float4 o;
        o.x = acc[co][0] + bc;
        o.y = acc[co][1] + bc;
        o.z = acc[co][2] + bc;
        o.w = acc[co][3] + bc;
        *reinterpret_cast<float4*>(&y[obase + (size_t)co * co_stride]) = o;
    }
}

}  // namespace

extern "C" void kernel_launch(void* const* d_in, const int* in_sizes, int n_in,
                              void* d_out, int out_size, void* d_ws, size_t ws_size,
                              hipStream_t stream) {
    const float* x    = (const float*)d_in[0];
    const float* w    = (const float*)d_in[1];
    const float* bias = (const float*)d_in[2];
    float* y          = (float*)d_out;

    dim3 block(8, 32, 1);                 // (wo-quad, ho)
    dim3 grid(kD2, kD1, kB);              // (v, u, b)
    hipLaunchKernelGGL(conv4d_strang, grid, block, 0, stream, x, w, bias, y);
}

// Round 3
// 155.741 us; speedup vs baseline: 1.9483x; 1.9483x over previous
//
#include <hip/hip_runtime.h>

namespace {

constexpr int kB = 4, kCin = 4, kCout = 4;
constexpr int kD1 = 32, kD2 = 32, kH = 64, kW = 64;
constexpr int kHO = kH / 2, kWO = kW / 2;              // 32, 32
constexpr int kSlice = kH * kW;                        // 4096 floats per (d1,d2) slice
constexpr int kCiStride = kD1 * kD2 * kSlice;          // ci stride in x (floats)
constexpr int kWElems = kCout * kCin * 3 * 3 * 2 * 2;  // 576

__global__ __launch_bounds__(256)
void conv4d_strang(const float* __restrict__ x,
                   const float* __restrict__ w,
                   const float* __restrict__ bias,
                   float* __restrict__ y)
{
    // Tiny weight tensor staged once into LDS; all reads are wave-uniform
    // (broadcast, conflict-free).
    __shared__ float wlds[kWElems];
    {
        const int tid = threadIdx.y * 16 + threadIdx.x;
        for (int i = tid; i < kWElems; i += 256) wlds[i] = w[i];
    }
    __syncthreads();

    // ---- XCD-chunked decode -------------------------------------------
    // Round-robin HW mapping assigns XCD = orig % 8. We make each XCD own
    // one (b, h-half) chunk: its 32 MB of x is private to that XCD's L2
    // (H is not convolved -> h-halves independent). Within a chunk the
    // work order is v-fastest, then u, keeping the (u,v) halo L2-resident.
    const unsigned orig = blockIdx.x;       // 0..8191
    const unsigned z    = orig & 7;         // chunk id = (b, ht)
    const unsigned rem  = orig >> 3;        // 0..1023 position within chunk
    const int u  = rem >> 5;                // 0..31
    const int v  = rem & 31;                // 0..31
    const int b  = z >> 1;                  // 0..3
    const int ht = z & 1;                   // h-half

    const int wq = threadIdx.x;             // 0..15  -> 4 input cols, 2 outputs
    const int hy = threadIdx.y;             // 0..15
    const int ho = ht * 16 + hy;            // 0..31
    const int h0 = 2 * ho;
    const int w0 = 4 * wq;
    const int toff = h0 * kW + w0;          // per-thread 32-bit elem offset in a slice

    float acc[kCout][2];
    #pragma unroll
    for (int co = 0; co < kCout; ++co) {
        const float bb = bias[co];          // uniform address -> scalar load
        acc[co][0] = bb;
        acc[co][1] = bb;
    }

    #pragma unroll
    for (int ku = 0; ku < 3; ++ku) {
        const int d1 = u + ku - 1;
        if (d1 < 0 || d1 >= kD1) continue;            // wave-uniform
        #pragma unroll
        for (int kv = 0; kv < 3; ++kv) {
            const int d2 = v + kv - 1;
            if (d2 < 0 || d2 >= kD2) continue;        // wave-uniform
            // Block-uniform slice base (stays in SGPRs).
            const float* sbase = x + ((size_t)(b * kCin * kD1 * kD2)
                                      + (size_t)(d1 * kD2 + d2)) * kSlice;
            #pragma unroll
            for (int ci = 0; ci < kCin; ++ci) {
                const float* sp = sbase + (size_t)ci * kCiStride;  // uniform
                const float4 r0 = *reinterpret_cast<const float4*>(sp + toff);
                const float4 r1 = *reinterpret_cast<const float4*>(sp + toff + kW);
                #pragma unroll
                for (int co = 0; co < kCout; ++co) {
                    const float4 wv = *reinterpret_cast<const float4*>(
                        &wlds[(((co * kCin + ci) * 3 + ku) * 3 + kv) * 4]);
                    acc[co][0] += r0.x * wv.x + r0.y * wv.y + r1.x * wv.z + r1.y * wv.w;
                    acc[co][1] += r0.z * wv.x + r0.w * wv.y + r1.z * wv.z + r1.w * wv.w;
                }
            }
        }
    }

    const size_t co_stride = (size_t)kD1 * kD2 * kHO * kWO;  // 1,048,576
    float* yp = y + (((size_t)(b * kCout * kD1) + (size_t)u) * kD2 + v) * (size_t)(kHO * kWO)
                  + (size_t)ho * kWO + 2 * wq;
    #pragma unroll
    for (int co = 0; co < kCout; ++co) {
        float2 o;
        o.x = acc[co][0];
        o.y = acc[co][1];
        *reinterpret_cast<float2*>(yp + (size_t)co * co_stride) = o;
    }
}

}  // namespace

extern "C" void kernel_launch(void* const* d_in, const int* in_sizes, int n_in,
                              void* d_out, int out_size, void* d_ws, size_t ws_size,
                              hipStream_t stream) {
    const float* x    = (const float*)d_in[0];
    const float* w    = (const float*)d_in[1];
    const float* bias = (const float*)d_in[2];
    float* y          = (float*)d_out;

    dim3 block(16, 16, 1);                 // (w-quad, h-row)
    dim3 grid(kB * 2 * kD1 * kD2, 1, 1);   // 8192 blocks, swizzle-decoded in-kernel
    hipLaunchKernelGGL(conv4d_strang, grid, block, 0, stream, x, w, bias, y);
}

// Round 4
// 129.098 us; speedup vs baseline: 2.3504x; 1.2064x over previous
//
#include <hip/hip_runtime.h>

namespace {

typedef float v2f __attribute__((ext_vector_type(2)));
typedef float v4f __attribute__((ext_vector_type(4)));

constexpr int kB = 4, kCin = 4, kCout = 4;
constexpr int kD1 = 32, kD2 = 32, kH = 64, kW = 64;
constexpr int kHO = 32, kWO = 32;
constexpr int kSlice = kH * kW;                       // 4096
constexpr size_t kCiStride = (size_t)kD1 * kD2 * kSlice;

__global__ __launch_bounds__(256)
void conv4d_strang(const float* __restrict__ x, const float* __restrict__ w,
                   const float* __restrict__ bias, float* __restrict__ y)
{
    // ---- XCD-chunked decode: chunk=(b,ht) -> one XCD owns 32MB of x ----
    const unsigned orig  = blockIdx.x;      // 0..2047
    const unsigned chunk = orig & 7;        // XCD id under round-robin
    const unsigned rem   = orig >> 3;       // 0..255, v-tile fastest
    const int tu = rem >> 4;                // 0..15
    const int tv = rem & 15;                // 0..15
    const int b  = chunk >> 1;
    const int ht = chunk & 1;
    const int u0 = 2 * tu, v0 = 2 * tv;     // 2x2 (u,v) register tile

    const int wq = threadIdx.x;             // 0..15 -> outputs wo=2wq,2wq+1
    const int hy = threadIdx.y;             // 0..15
    const int ho = ht * 16 + hy;            // 0..31
    const int toff = (2 * ho) * kW + 4 * wq;

    // acc[uu][vv][co][wo] : v2f = (even-tap partial, odd-tap partial)
    v2f acc[2][2][kCout][2];
    #pragma unroll
    for (int uu = 0; uu < 2; ++uu)
        #pragma unroll
        for (int vv = 0; vv < 2; ++vv)
            #pragma unroll
            for (int co = 0; co < kCout; ++co) {
                acc[uu][vv][co][0] = (v2f){0.f, 0.f};
                acc[uu][vv][co][1] = (v2f){0.f, 0.f};
            }

    const float* xb = x + (size_t)b * kCin * kCiStride + toff;

    #pragma unroll
    for (int e1 = 0; e1 < 4; ++e1) {
        const int d1 = u0 + e1 - 1;
        if (d1 < 0 || d1 >= kD1) continue;            // wave-uniform
        #pragma unroll
        for (int e2 = 0; e2 < 4; ++e2) {
            const int d2 = v0 + e2 - 1;
            if (d2 < 0 || d2 >= kD2) continue;        // wave-uniform
            const float* sp0 = xb + (size_t)(d1 * kD2 + d2) * kSlice;
            #pragma unroll
            for (int ci = 0; ci < kCin; ++ci) {
                const float* sp = sp0 + (size_t)ci * kCiStride;
                const v4f r0 = *reinterpret_cast<const v4f*>(sp);        // h0 row
                const v4f r1 = *reinterpret_cast<const v4f*>(sp + kW);   // h0+1 row
                #pragma unroll
                for (int uu = 0; uu < 2; ++uu) {
                    const int ku = e1 - uu;
                    if (ku < 0 || ku > 2) continue;   // compile-time
                    #pragma unroll
                    for (int vv = 0; vv < 2; ++vv) {
                        const int kv = e2 - vv;
                        if (kv < 0 || kv > 2) continue;  // compile-time
                        #pragma unroll
                        for (int co = 0; co < kCout; ++co) {
                            // Fully constant index -> scalar (s_load) weight reads.
                            const float* wp = w + (((co * kCin + ci) * 3 + ku) * 3 + kv) * 4;
                            const v2f w01 = {wp[0], wp[1]};   // h-tap 0, w-taps 0,1
                            const v2f w23 = {wp[2], wp[3]};   // h-tap 1, w-taps 0,1
                            acc[uu][vv][co][0] =
                                __builtin_elementwise_fma(r0.xy, w01, acc[uu][vv][co][0]);
                            acc[uu][vv][co][0] =
                                __builtin_elementwise_fma(r1.xy, w23, acc[uu][vv][co][0]);
                            acc[uu][vv][co][1] =
                                __builtin_elementwise_fma(r0.zw, w01, acc[uu][vv][co][1]);
                            acc[uu][vv][co][1] =
                                __builtin_elementwise_fma(r1.zw, w23, acc[uu][vv][co][1]);
                        }
                    }
                }
            }
        }
    }

    #pragma unroll
    for (int co = 0; co < kCout; ++co) {
        const float bb = bias[co];
        #pragma unroll
        for (int uu = 0; uu < 2; ++uu)
            #pragma unroll
            for (int vv = 0; vv < 2; ++vv) {
                v2f o;
                o.x = acc[uu][vv][co][0].x + acc[uu][vv][co][0].y + bb;
                o.y = acc[uu][vv][co][1].x + acc[uu][vv][co][1].y + bb;
                float* yp = y
                    + ((((size_t)(b * kCout + co) * kD1 + (u0 + uu)) * kD2 + (v0 + vv)) * kHO + ho) * kWO
                    + 2 * wq;
                *reinterpret_cast<v2f*>(yp) = o;
            }
    }
}

}  // namespace

extern "C" void kernel_launch(void* const* d_in, const int* in_sizes, int n_in,
                              void* d_out, int out_size, void* d_ws, size_t ws_size,
                              hipStream_t stream) {
    const float* x    = (const float*)d_in[0];
    const float* w    = (const float*)d_in[1];
    const float* bias = (const float*)d_in[2];
    float* y          = (float*)d_out;

    dim3 block(16, 16, 1);
    dim3 grid(kB * 2 * 16 * 16, 1, 1);   // 2048 blocks, decoded in-kernel
    hipLaunchKernelGGL(conv4d_strang, grid, block, 0, stream, x, w, bias, y);
}